// Round 4
// baseline (381.304 us; speedup 1.0000x reference)
//
#include <hip/hip_runtime.h>
#include <cstdint>

#define SEQn   2048
#define NHn    16
#define HDn    128
#define DMn    2048   // NH*HD
#define HIDn   2048
#define BATCHn 2
#define WINn   256
#define MROWS  (BATCHn*SEQn)  // 4096
#define WELEMS ((size_t)HIDn * DMn)

typedef short s16x8 __attribute__((ext_vector_type(8)));  // 8 bf16 (4 VGPRs)
typedef float f32x4 __attribute__((ext_vector_type(4)));  // MFMA accumulator

__device__ __forceinline__ float bf2f(ushort x) {
    union { uint u; float f; } v; v.u = ((uint)x) << 16; return v.f;
}
__device__ __forceinline__ ushort f2bf(float f) {
    union { float f; uint u; } v; v.f = f;
    uint u = v.u;
    return (ushort)((u + 0x7FFFu + ((u >> 16) & 1u)) >> 16);  // RNE
}

// Direct global->LDS DMA, 16B per lane. Dest must be wave-uniform base,
// lane's 16B lands at base + lane*16 (linear! no padding allowed).
#define GLOAD_LDS16(g, l) __builtin_amdgcn_global_load_lds(                   \
    (const __attribute__((address_space(1))) unsigned int*)(g),               \
    (__attribute__((address_space(3))) unsigned int*)(l), 16, 0, 0)

// Compiler fence: no memory op or instruction crosses (rule #18 discipline —
// raw s_barrier is NOT a compiler fence; C++ ds_reads would hoist past it).
#define FENCE() do { asm volatile("" ::: "memory");                           \
                     __builtin_amdgcn_sched_barrier(0); } while (0)

// --- ONE up-front dispatch: z=0..3 transpose {WQ,WK,WV,WO} -> WT slabs,
//     z=4: x fp32 -> bf16.  r13: 64x64 tiles (4x fewer blocks, 256B-coalesced
//     reads, 128B-coalesced writes vs the old 64B chunks). ----------------
__global__ __launch_bounds__(256)
void transpose_all_kernel(const float* __restrict__ WQ, const float* __restrict__ WK,
                          const float* __restrict__ WV, const float* __restrict__ WO,
                          ushort* __restrict__ WT,
                          const float* __restrict__ x, ushort* __restrict__ xb)
{
    const int tid = threadIdx.y * 32 + threadIdx.x;
    if (blockIdx.z == 4) {
        const int bid = blockIdx.y * 32 + blockIdx.x;     // 0..1023
        const size_t b0 = (size_t)bid * 8192;
        #pragma unroll
        for (int i = 0; i < 4; ++i) {
            const size_t base = b0 + i * 2048 + tid * 8;
            const float4 a0 = *reinterpret_cast<const float4*>(x + base);
            const float4 a1 = *reinterpret_cast<const float4*>(x + base + 4);
            ushort4 o0, o1;
            o0.x = f2bf(a0.x); o0.y = f2bf(a0.y); o0.z = f2bf(a0.z); o0.w = f2bf(a0.w);
            o1.x = f2bf(a1.x); o1.y = f2bf(a1.y); o1.z = f2bf(a1.z); o1.w = f2bf(a1.w);
            *reinterpret_cast<ushort4*>(xb + base)     = o0;
            *reinterpret_cast<ushort4*>(xb + base + 4) = o1;
        }
        return;
    }
    __shared__ ushort t[64][72];   // stride 72 ushorts: ushort4-aligned reads
    const float* src = (blockIdx.z == 0) ? WQ : (blockIdx.z == 1) ? WK
                     : (blockIdx.z == 2) ? WV : WO;
    ushort* dst = WT + (size_t)blockIdx.z * WELEMS;
    const int n0 = blockIdx.x * 64;
    const int k0 = blockIdx.y * 64;
    const int c  = tid & 63;          // n-offset (coalesced read)
    const int rr = tid >> 6;          // 0..3
    #pragma unroll
    for (int i = 0; i < 16; ++i) {
        const int r = i * 4 + rr;     // k-offset
        t[c][r] = f2bf(src[(size_t)(k0 + r) * 2048 + n0 + c]);
    }
    __syncthreads();
    const int rowg = tid >> 4;        // 0..15  (n rows)
    const int kc   = (tid & 15) * 4;  // k chunk (ushort4)
    #pragma unroll
    for (int rr2 = 0; rr2 < 4; ++rr2) {
        const int arow = rowg + rr2 * 16;
        const ushort4 v = *reinterpret_cast<const ushort4*>(&t[arow][kc]);
        *reinterpret_cast<ushort4*>(dst + (size_t)(n0 + arow) * 2048 + k0 + kc) = v;
    }
}

// ------- single transpose+convert (fallback path only) -----------------------
__global__ __launch_bounds__(256)
void transpose_cvt_kernel(const float* __restrict__ src, ushort* __restrict__ dst)
{
    __shared__ ushort t[32][33];
    const int tx = threadIdx.x, ty = threadIdx.y;
    const int n  = blockIdx.x * 32 + tx;
    const int k0 = blockIdx.y * 32;
    #pragma unroll
    for (int r = ty; r < 32; r += 8)
        t[r][tx] = f2bf(src[(size_t)(k0 + r) * 2048 + n]);
    __syncthreads();
    const int k  = k0 + tx;
    const int nb = blockIdx.x * 32;
    #pragma unroll
    for (int r = ty; r < 32; r += 8)
        dst[(size_t)(nb + r) * 2048 + k] = t[tx][r];
}

// -------- fused QKV GEMM + fused RoPE epilogue ------------------------------
// r12 pipeline (T4 counted-vmcnt dbuf, 896 TF = structure ceiling) + r13 T1
// XCD-chunked swizzle: each XCD gets 4 contiguous m-panels (2MB A, L2-fit).
template<int ABF16>
__global__ __launch_bounds__(256)
void gemm_qkv_kernel(const void* __restrict__ Araw, const ushort* __restrict__ WT,
                     const float* __restrict__ bQ, const float* __restrict__ bK,
                     const float* __restrict__ bV,
                     ushort* __restrict__ Qb, ushort* __restrict__ Kb,
                     ushort* __restrict__ Vt)
{
    // slot s: As = smem + s*16384 (128x64), Bs = +8192. ctile aliases slot 0.
    __shared__ __align__(16) ushort smem[32768];   // 64 KB
    const int tid = threadIdx.x;
    // T1: nwg = 48*32 = 1536, cpx = 192 -> XCD k owns by in [4k, 4k+4)
    const int lin = blockIdx.y * 48 + blockIdx.x;
    const int swz = (lin & 7) * 192 + (lin >> 3);
    const int m0  = (swz / 48) * 128;
    const int n0g = (swz % 48) * 128;          // 0..6143
    const int sel = n0g >> 11;                 // 0=Q 1=K 2=V
    const int n0  = n0g & 2047;
    const ushort* BT  = WT + (size_t)sel * WELEMS;
    const float* bias = (sel == 0) ? bQ : (sel == 1) ? bK : bV;
    const int w  = tid >> 6;
    const int l  = tid & 63;
    const int wy = w >> 1, wx = w & 1;
    const int q  = l >> 4, lm = l & 15;
    const int sw = lm & 7;                     // read-side XOR (row & 7 == lm & 7)

    f32x4 acc[4][4];
    #pragma unroll
    for (int i = 0; i < 4; ++i)
        #pragma unroll
        for (int j = 0; j < 4; ++j) acc[i][j] = (f32x4)0.0f;

    auto stage = [&](int slot, int kt) {
        ushort* AsS = smem + slot * 16384;
        ushort* BsS = AsS + 8192;
        if (ABF16) {
            #pragma unroll
            for (int it = 0; it < 4; ++it) {
                const int v = it * 256 + tid;       // 16B-chunk index 0..1023
                const int r = v >> 3;
                const int cs = ((v & 7) ^ (r & 7)) << 3;   // pre-swizzled src col
                const ushort* gA = (const ushort*)Araw + (size_t)(m0 + r) * HIDn + kt + cs;
                const ushort* gB = BT + (size_t)(n0 + r) * HIDn + kt + cs;
                GLOAD_LDS16(gA, AsS + (it * 256 + w * 64) * 8);
                GLOAD_LDS16(gB, BsS + (it * 256 + w * 64) * 8);
            }
        } else {
            #pragma unroll
            for (int it = 0; it < 4; ++it) {
                const int v = it * 256 + tid;
                const int r = v >> 3;
                const int c = (v & 7) << 3;
                const float* Af = (const float*)Araw + (size_t)(m0 + r) * HIDn + kt + c;
                const float4 a0 = *reinterpret_cast<const float4*>(Af);
                const float4 a1 = *reinterpret_cast<const float4*>(Af + 4);
                ushort* d = &AsS[(size_t)(v ^ (r & 7)) * 8];   // swizzled dest chunk
                d[0] = f2bf(a0.x); d[1] = f2bf(a0.y); d[2] = f2bf(a0.z); d[3] = f2bf(a0.w);
                d[4] = f2bf(a1.x); d[5] = f2bf(a1.y); d[6] = f2bf(a1.z); d[7] = f2bf(a1.w);
                const int cs = ((v & 7) ^ (r & 7)) << 3;
                const ushort* gB = BT + (size_t)(n0 + r) * HIDn + kt + cs;
                GLOAD_LDS16(gB, BsS + (it * 256 + w * 64) * 8);
            }
        }
    };

    auto compute = [&](int slot) {
        const ushort* AsS = smem + slot * 16384;
        const ushort* BsS = AsS + 8192;
        #pragma unroll
        for (int ks = 0; ks < 2; ++ks) {
            s16x8 af[4], bfv[4];
            #pragma unroll
            for (int im = 0; im < 4; ++im) {
                const int arow = wy * 64 + im * 16 + lm;
                af[im] = *reinterpret_cast<const s16x8*>(
                    &AsS[arow * 64 + (((ks * 4 + q) ^ sw) << 3)]);
            }
            #pragma unroll
            for (int in = 0; in < 4; ++in) {
                const int brow = wx * 64 + in * 16 + lm;
                bfv[in] = *reinterpret_cast<const s16x8*>(
                    &BsS[brow * 64 + (((ks * 4 + q) ^ sw) << 3)]);
            }
            __builtin_amdgcn_s_setprio(1);
            #pragma unroll
            for (int im = 0; im < 4; ++im)
                #pragma unroll
                for (int in = 0; in < 4; ++in)
                    acc[im][in] = __builtin_amdgcn_mfma_f32_16x16x32_bf16(af[im], bfv[in], acc[im][in], 0, 0, 0);
            __builtin_amdgcn_s_setprio(0);
        }
    };

    const int NT = HIDn / 64;   // 32
    stage(0, 0);
    int cur = 0;
    for (int t = 0; t < NT - 1; ++t) {
        stage(cur ^ 1, (t + 1) * 64);
        if (ABF16) asm volatile("s_waitcnt vmcnt(8)" ::: "memory");
        else       asm volatile("s_waitcnt vmcnt(4)" ::: "memory");
        __builtin_amdgcn_s_barrier();
        FENCE();
        compute(cur);
        FENCE();
        if (!ABF16) asm volatile("s_waitcnt lgkmcnt(0)" ::: "memory");
        __builtin_amdgcn_s_barrier();
        FENCE();
        cur ^= 1;
    }
    asm volatile("s_waitcnt vmcnt(0)" ::: "memory");
    __builtin_amdgcn_s_barrier();
    FENCE();
    compute(cur);
    __syncthreads();   // full fence before ctile aliases As/Bs

    if (sel == 2) {
        // LDS-transposed coalesced V store: ctile[d][s], stride 136 (2-way free).
        ushort* ctile = smem;
        #pragma unroll
        for (int in = 0; in < 4; ++in) {
            const int col = wx * 64 + in * 16 + lm;          // d
            const float bv = bias[n0 + col];
            #pragma unroll
            for (int im = 0; im < 4; ++im) {
                const int row0 = wy * 64 + im * 16 + q * 4;  // s-local
                #pragma unroll
                for (int r = 0; r < 4; ++r)
                    ctile[col * 136 + row0 + r] = f2bf(acc[im][in][r] + bv);
            }
        }
        __syncthreads();
        const int hh = n0 >> 7;
        const int bb = m0 >> 11;
        const int s0 = m0 & (SEQn - 1);
        const int st = (tid & 15) * 8;
        const int d0 = tid >> 4;            // 0..15
        #pragma unroll
        for (int db = 0; db < 8; ++db) {
            const int d = d0 + db * 16;
            const ushort4 v0 = *reinterpret_cast<const ushort4*>(&ctile[d * 136 + st]);
            const ushort4 v1 = *reinterpret_cast<const ushort4*>(&ctile[d * 136 + st + 4]);
            ushort* dstp = Vt + (((size_t)(bb * NHn + hh)) * HDn + d) * SEQn + s0 + st;
            *reinterpret_cast<ushort4*>(dstp)     = v0;
            *reinterpret_cast<ushort4*>(dstp + 4) = v1;
        }
    } else {
        ushort* ctile = smem;                  // 128 rows x stride 136
        #pragma unroll
        for (int in = 0; in < 4; ++in) {
            const int col = wx * 64 + in * 16 + lm;
            const float bv = bias[n0 + col];
            #pragma unroll
            for (int im = 0; im < 4; ++im) {
                const int row0 = wy * 64 + im * 16 + q * 4;
                #pragma unroll
                for (int r = 0; r < 4; ++r)
                    ctile[(row0 + r) * 136 + col] = f2bf(acc[im][in][r] + bv);
            }
        }
        __syncthreads();
        ushort* dst = (sel == 0) ? Qb : Kb;
        const int d = tid & 63;
        const float invf = exp2f(-(float)d * 0.20762050593046f);  // 10000^(-d/64)
        for (int r = tid >> 6; r < 128; r += 4) {
            const int s = (m0 + r) & (SEQn - 1);
            const float ang = (float)s * invf;
            float sn, cs;
            __sincosf(ang, &sn, &cs);
            const float t1 = bf2f(ctile[r * 136 + d]);
            const float t2 = bf2f(ctile[r * 136 + 64 + d]);
            const size_t base = (size_t)(m0 + r) * DMn + n0 + d;
            dst[base]      = f2bf(t1 * cs - t2 * sn);
            dst[base + 64] = f2bf(t1 * sn + t2 * cs);
        }
    }
}

// ---- final GEMM: out(4096x2048 fp32) = AO(bf16) * WT^T + bias (fp32) -------
// r13: 128x128 tile (was 64x128 — half the acc reuse), exact clone of the
// qkv T4 counted-vmcnt dbuf pipeline. Grid 16x32=512, T1 XCD swizzle.
__global__ __launch_bounds__(256)
void gemm_out_kernel(const ushort* __restrict__ A, const ushort* __restrict__ BT,
                     const float* __restrict__ bias, float* __restrict__ C)
{
    __shared__ __align__(16) ushort smem[32768];   // 64 KB: 2 slots x (A 16K | B 16K)
    const int tid = threadIdx.x;
    // T1: nwg = 16*32 = 512, cpx = 64 -> XCD k owns by in [4k, 4k+4)
    const int lin = blockIdx.y * 16 + blockIdx.x;
    const int swz = (lin & 7) * 64 + (lin >> 3);
    const int m0 = (swz >> 4) * 128;
    const int n0 = (swz & 15) * 128;
    const int w  = tid >> 6;
    const int l  = tid & 63;
    const int wy = w >> 1, wx = w & 1;
    const int q  = l >> 4, lm = l & 15;
    const int sw = lm & 7;

    f32x4 acc[4][4];
    #pragma unroll
    for (int i = 0; i < 4; ++i)
        #pragma unroll
        for (int j = 0; j < 4; ++j) acc[i][j] = (f32x4)0.0f;

    auto stage = [&](int slot, int kt) {
        ushort* AsS = smem + slot * 16384;
        ushort* BsS = AsS + 8192;
        #pragma unroll
        for (int it = 0; it < 4; ++it) {
            const int v = it * 256 + tid;
            const int r = v >> 3;
            const int cs = ((v & 7) ^ (r & 7)) << 3;
            GLOAD_LDS16(A  + (size_t)(m0 + r) * DMn + kt + cs,
                        AsS + (it * 256 + w * 64) * 8);
            GLOAD_LDS16(BT + (size_t)(n0 + r) * DMn + kt + cs,
                        BsS + (it * 256 + w * 64) * 8);
        }
    };

    auto compute = [&](int slot) {
        const ushort* AsS = smem + slot * 16384;
        const ushort* BsS = AsS + 8192;
        #pragma unroll
        for (int ks = 0; ks < 2; ++ks) {
            s16x8 af[4], bfv[4];
            #pragma unroll
            for (int im = 0; im < 4; ++im) {
                const int arow = wy * 64 + im * 16 + lm;
                af[im] = *reinterpret_cast<const s16x8*>(
                    &AsS[arow * 64 + (((ks * 4 + q) ^ sw) << 3)]);
            }
            #pragma unroll
            for (int in = 0; in < 4; ++in) {
                const int brow = wx * 64 + in * 16 + lm;
                bfv[in] = *reinterpret_cast<const s16x8*>(
                    &BsS[brow * 64 + (((ks * 4 + q) ^ sw) << 3)]);
            }
            __builtin_amdgcn_s_setprio(1);
            #pragma unroll
            for (int im = 0; im < 4; ++im)
                #pragma unroll
                for (int in = 0; in < 4; ++in)
                    acc[im][in] = __builtin_amdgcn_mfma_f32_16x16x32_bf16(af[im], bfv[in], acc[im][in], 0, 0, 0);
            __builtin_amdgcn_s_setprio(0);
        }
    };

    const int NT = DMn / 64;   // 32
    stage(0, 0);
    int cur = 0;
    for (int t = 0; t < NT - 1; ++t) {
        stage(cur ^ 1, (t + 1) * 64);
        asm volatile("s_waitcnt vmcnt(8)" ::: "memory");
        __builtin_amdgcn_s_barrier();
        FENCE();
        compute(cur);
        FENCE();
        __builtin_amdgcn_s_barrier();
        FENCE();
        cur ^= 1;
    }
    asm volatile("s_waitcnt vmcnt(0)" ::: "memory");
    __builtin_amdgcn_s_barrier();
    FENCE();
    compute(cur);

    #pragma unroll
    for (int in = 0; in < 4; ++in) {
        const int gcol = n0 + wx * 64 + in * 16 + lm;
        const float bv = bias[gcol];
        #pragma unroll
        for (int im = 0; im < 4; ++im) {
            const int grow0 = m0 + wy * 64 + im * 16 + q * 4;
            #pragma unroll
            for (int r = 0; r < 4; ++r)
                C[(size_t)(grow0 + r) * HIDn + gcol] = acc[im][in][r] + bv;
        }
    }
}

// -------- MFMA flash attention: r4 structure + V-prefetch + T5 setprio ------
// r13: + T1 XCD-chunked swizzle — each XCD gets 128 contiguous blocks =
// 4 (b,h) groups -> K+V (4MB) L2-resident per XCD.
__global__ __launch_bounds__(256)
void attn_mfma_kernel(const ushort* Q, const ushort* __restrict__ K,
                      const ushort* __restrict__ Vt, const float* __restrict__ kw,
                      ushort* AO)
{
    __shared__ ushort plds[4][16 * 40];   // per-wave P tile, stride 40 (2-way = free)
    const int w  = threadIdx.x >> 6;
    const int l  = threadIdx.x & 63;
    const int q  = l >> 4, lm = l & 15;
    const int bid = blockIdx.x;                     // nwg = 1024, cpx = 128
    const int swzb = (bid & 7) * 128 + (bid >> 3);
    const int gw = swzb * 4 + w;     // b(1) | h(4) | qt(7)
    const int qt = gw & 127;
    const int h  = (gw >> 7) & (NHn - 1);
    const int b  = gw >> 11;
    const int q0 = qt * 16;
    const float f = kw[h] * 0.08838834764831845f;   // kw * HD^-0.5

    s16x8 qf[4];
    const size_t qbase = ((size_t)(b * SEQn + q0 + lm)) * DMn + h * HDn;
    #pragma unroll
    for (int ks = 0; ks < 4; ++ks)
        qf[ks] = *reinterpret_cast<const s16x8*>(Q + qbase + ks * 32 + q * 8);

    f32x4 O[8];
    #pragma unroll
    for (int nt = 0; nt < 8; ++nt) O[nt] = (f32x4)0.0f;
    float m[4]    = {-1e30f, -1e30f, -1e30f, -1e30f};
    float lsum[4] = {0.f, 0.f, 0.f, 0.f};

    const int lo = q0 - WINn;
    const int c0 = lo > 0 ? (lo & ~31) : 0;
    const int nch = (q0 + 16 - c0 + 31) >> 5;

    const size_t kbh = ((size_t)(b * SEQn)) * DMn + h * HDn;
    const size_t vbh = ((size_t)(b * NHn + h)) * HDn * SEQn;

    for (int c = 0; c < nch; ++c) {
        const int kc = c0 + c * 32;
        // ---- prefetch V frags (independent of softmax) ----
        s16x8 vf[8];
        #pragma unroll
        for (int nt = 0; nt < 8; ++nt)
            vf[nt] = *reinterpret_cast<const s16x8*>(
                Vt + vbh + (size_t)(nt * 16 + lm) * SEQn + kc + q * 8);
        // ---- QK^T: two 16-key tiles, 4 chained k-MFMAs each ----
        f32x4 S[2];
        #pragma unroll
        for (int t = 0; t < 2; ++t) {
            f32x4 acc = (f32x4)0.0f;
            const size_t krow = kbh + (size_t)(kc + t * 16 + lm) * DMn;
            s16x8 kf[4];
            #pragma unroll
            for (int ks = 0; ks < 4; ++ks)
                kf[ks] = *reinterpret_cast<const s16x8*>(K + krow + ks * 32 + q * 8);
            __builtin_amdgcn_s_setprio(1);
            #pragma unroll
            for (int ks = 0; ks < 4; ++ks)
                acc = __builtin_amdgcn_mfma_f32_16x16x32_bf16(qf[ks], kf[ks], acc, 0, 0, 0);
            __builtin_amdgcn_s_setprio(0);
            S[t] = acc;
        }
        // ---- scale, mask, online softmax ----
        const int j0 = kc + lm, j1 = kc + 16 + lm;
        #pragma unroll
        for (int r = 0; r < 4; ++r) {
            const int i = q0 + q * 4 + r;
            float v0 = S[0][r] * f;
            float v1 = S[1][r] * f;
            if (j0 > i || j0 < i - WINn) v0 = -1e30f;
            if (j1 > i || j1 < i - WINn) v1 = -1e30f;
            float mx = fmaxf(v0, v1);
            #pragma unroll
            for (int off = 8; off > 0; off >>= 1)
                mx = fmaxf(mx, __shfl_xor(mx, off));
            const float mn = fmaxf(m[r], mx);
            const float alpha = __expf(m[r] - mn);
            m[r] = mn;
            const ushort h0 = f2bf(__expf(v0 - mn));
            const ushort h1 = f2bf(__expf(v1 - mn));
            plds[w][(q * 4 + r) * 40 + lm]      = h0;
            plds[w][(q * 4 + r) * 40 + 16 + lm] = h1;
            float ps = bf2f(h0) + bf2f(h1);
            #pragma unroll
            for (int off = 8; off > 0; off >>= 1)
                ps += __shfl_xor(ps, off);
            lsum[r] = lsum[r] * alpha + ps;
            #pragma unroll
            for (int nt = 0; nt < 8; ++nt) O[nt][r] *= alpha;
        }
        // ---- P -> A-frag via per-wave LDS round trip; P·V ----
        const s16x8 pf = *reinterpret_cast<const s16x8*>(&plds[w][lm * 40 + q * 8]);
        __builtin_amdgcn_s_setprio(1);
        #pragma unroll
        for (int nt = 0; nt < 8; ++nt)
            O[nt] = __builtin_amdgcn_mfma_f32_16x16x32_bf16(pf, vf[nt], O[nt], 0, 0, 0);
        __builtin_amdgcn_s_setprio(0);
    }
    #pragma unroll
    for (int r = 0; r < 4; ++r) {
        const float inv = 1.0f / lsum[r];
        const size_t orow = ((size_t)(b * SEQn + q0 + q * 4 + r)) * DMn + h * HDn;
        #pragma unroll
        for (int nt = 0; nt < 8; ++nt)
            AO[orow + nt * 16 + lm] = f2bf(O[nt][r] * inv);
    }
}

extern "C" void kernel_launch(void* const* d_in, const int* in_sizes, int n_in,
                              void* d_out, int out_size, void* d_ws, size_t ws_size,
                              hipStream_t stream)
{
    (void)in_sizes; (void)n_in; (void)out_size;
    const float* x  = (const float*)d_in[0];
    const float* WQ = (const float*)d_in[1];
    const float* bQ = (const float*)d_in[2];
    const float* WK = (const float*)d_in[3];
    const float* bK = (const float*)d_in[4];
    const float* WV = (const float*)d_in[5];
    const float* bV = (const float*)d_in[6];
    const float* WO = (const float*)d_in[7];
    const float* bO = (const float*)d_in[8];
    const float* kw = (const float*)d_in[9];
    float* out = (float*)d_out;

    // Full path: Qb/Kb/Vt (48 MB) + WT 4 slabs (32 MB) + xb (16 MB) = 96 MB.
    // Fallback (ws < 96 MB): 3 slabs, fp32-A QKV GEMM, late WO transpose.
    char* ws = (char*)d_ws;
    const size_t AELEMS = (size_t)MROWS * DMn;         // 4096*2048
    ushort* Qb = (ushort*)ws;                          // also AO (in-place)
    ushort* Kb = (ushort*)(ws + AELEMS * 2);
    ushort* Vt = (ushort*)(ws + AELEMS * 4);           // [b][h][d][s]
    ushort* WT = (ushort*)(ws + AELEMS * 6);           // up to 4 x 2048x2048 bf16
    const size_t FULL = AELEMS * 6 + WELEMS * 8 + AELEMS * 2;   // 96 MB
    const bool have_full = ws_size >= FULL;
    ushort* xb = (ushort*)(ws + AELEMS * 6 + WELEMS * 8);

    const dim3 tblk(32, 8);

    if (have_full) {
        transpose_all_kernel<<<dim3(32, 32, 5), tblk, 0, stream>>>(WQ, WK, WV, WO, WT, x, xb);
        gemm_qkv_kernel<1><<<dim3(3 * DMn / 128, MROWS / 128), 256, 0, stream>>>(
            xb, WT, bQ, bK, bV, Qb, Kb, Vt);
        attn_mfma_kernel<<<dim3(BATCHn * NHn * (SEQn / 16) / 4), 256, 0, stream>>>(Qb, Kb, Vt, kw, Qb);
        gemm_out_kernel<<<dim3(HIDn / 128, MROWS / 128), 256, 0, stream>>>(
            Qb, WT + 3 * WELEMS, bO, out);
    } else {
        transpose_all_kernel<<<dim3(32, 32, 3), tblk, 0, stream>>>(WQ, WK, WV, WO, WT, x, xb);
        gemm_qkv_kernel<0><<<dim3(3 * DMn / 128, MROWS / 128), 256, 0, stream>>>(
            x, WT, bQ, bK, bV, Qb, Kb, Vt);
        attn_mfma_kernel<<<dim3(BATCHn * NHn * (SEQn / 16) / 4), 256, 0, stream>>>(Qb, Kb, Vt, kw, Qb);
        transpose_cvt_kernel<<<dim3(64, 64), tblk, 0, stream>>>(WO, WT);
        gemm_out_kernel<<<dim3(HIDn / 128, MROWS / 128), 256, 0, stream>>>(Qb, WT, bO, out);
    }
}

// Round 5
// 365.878 us; speedup vs baseline: 1.0422x; 1.0422x over previous
//
#include <hip/hip_runtime.h>
#include <cstdint>

#define SEQn   2048
#define NHn    16
#define HDn    128
#define DMn    2048   // NH*HD
#define HIDn   2048
#define BATCHn 2
#define WINn   256
#define MROWS  (BATCHn*SEQn)  // 4096
#define WELEMS ((size_t)HIDn * DMn)

typedef short s16x8 __attribute__((ext_vector_type(8)));  // 8 bf16 (4 VGPRs)
typedef float f32x4 __attribute__((ext_vector_type(4)));  // MFMA accumulator

__device__ __forceinline__ float bf2f(ushort x) {
    union { uint u; float f; } v; v.u = ((uint)x) << 16; return v.f;
}
__device__ __forceinline__ ushort f2bf(float f) {
    union { float f; uint u; } v; v.f = f;
    uint u = v.u;
    return (ushort)((u + 0x7FFFu + ((u >> 16) & 1u)) >> 16);  // RNE
}

// Direct global->LDS DMA, 16B per lane. Dest must be wave-uniform base,
// lane's 16B lands at base + lane*16 (linear! no padding allowed).
#define GLOAD_LDS16(g, l) __builtin_amdgcn_global_load_lds(                   \
    (const __attribute__((address_space(1))) unsigned int*)(g),               \
    (__attribute__((address_space(3))) unsigned int*)(l), 16, 0, 0)

// Compiler fence: no memory op or instruction crosses (rule #18 discipline —
// raw s_barrier is NOT a compiler fence; C++ ds_reads would hoist past it).
#define FENCE() do { asm volatile("" ::: "memory");                           \
                     __builtin_amdgcn_sched_barrier(0); } while (0)

// --- ONE up-front dispatch: z=0..3 transpose {WQ,WK,WV,WO} -> WT slabs,
//     z=4: x fp32 -> bf16.  64x64 tiles, 256B-coalesced reads, 128B writes. --
__global__ __launch_bounds__(256)
void transpose_all_kernel(const float* __restrict__ WQ, const float* __restrict__ WK,
                          const float* __restrict__ WV, const float* __restrict__ WO,
                          ushort* __restrict__ WT,
                          const float* __restrict__ x, ushort* __restrict__ xb)
{
    const int tid = threadIdx.y * 32 + threadIdx.x;
    if (blockIdx.z == 4) {
        const int bid = blockIdx.y * 32 + blockIdx.x;     // 0..1023
        const size_t b0 = (size_t)bid * 8192;
        #pragma unroll
        for (int i = 0; i < 4; ++i) {
            const size_t base = b0 + i * 2048 + tid * 8;
            const float4 a0 = *reinterpret_cast<const float4*>(x + base);
            const float4 a1 = *reinterpret_cast<const float4*>(x + base + 4);
            ushort4 o0, o1;
            o0.x = f2bf(a0.x); o0.y = f2bf(a0.y); o0.z = f2bf(a0.z); o0.w = f2bf(a0.w);
            o1.x = f2bf(a1.x); o1.y = f2bf(a1.y); o1.z = f2bf(a1.z); o1.w = f2bf(a1.w);
            *reinterpret_cast<ushort4*>(xb + base)     = o0;
            *reinterpret_cast<ushort4*>(xb + base + 4) = o1;
        }
        return;
    }
    __shared__ ushort t[64][72];   // stride 72 ushorts: ushort4-aligned reads
    const float* src = (blockIdx.z == 0) ? WQ : (blockIdx.z == 1) ? WK
                     : (blockIdx.z == 2) ? WV : WO;
    ushort* dst = WT + (size_t)blockIdx.z * WELEMS;
    const int n0 = blockIdx.x * 64;
    const int k0 = blockIdx.y * 64;
    const int c  = tid & 63;          // n-offset (coalesced read)
    const int rr = tid >> 6;          // 0..3
    #pragma unroll
    for (int i = 0; i < 16; ++i) {
        const int r = i * 4 + rr;     // k-offset
        t[c][r] = f2bf(src[(size_t)(k0 + r) * 2048 + n0 + c]);
    }
    __syncthreads();
    const int rowg = tid >> 4;        // 0..15  (n rows)
    const int kc   = (tid & 15) * 4;  // k chunk (ushort4)
    #pragma unroll
    for (int rr2 = 0; rr2 < 4; ++rr2) {
        const int arow = rowg + rr2 * 16;
        const ushort4 v = *reinterpret_cast<const ushort4*>(&t[arow][kc]);
        *reinterpret_cast<ushort4*>(dst + (size_t)(n0 + arow) * 2048 + k0 + kc) = v;
    }
}

// ------- single transpose+convert (fallback path only) -----------------------
__global__ __launch_bounds__(256)
void transpose_cvt_kernel(const float* __restrict__ src, ushort* __restrict__ dst)
{
    __shared__ ushort t[32][33];
    const int tx = threadIdx.x, ty = threadIdx.y;
    const int n  = blockIdx.x * 32 + tx;
    const int k0 = blockIdx.y * 32;
    #pragma unroll
    for (int r = ty; r < 32; r += 8)
        t[r][tx] = f2bf(src[(size_t)(k0 + r) * 2048 + n]);
    __syncthreads();
    const int k  = k0 + tx;
    const int nb = blockIdx.x * 32;
    #pragma unroll
    for (int r = ty; r < 32; r += 8)
        dst[(size_t)(nb + r) * 2048 + k] = t[tx][r];
}

// -------- fused QKV GEMM + fused RoPE epilogue ------------------------------
// r12 pipeline (T4 counted-vmcnt dbuf, 115.1us = structure ceiling).
// r14: XCD swizzle REVERTED — natural x-fastest dispatch gives each XCD an
// n-stripe (6 B-tiles = 3MB, L2-resident); r4's m-chunked swizzle streamed
// all of B per XCD (FETCH 115->396MB, +10us). T1 axis must be the one whose
// per-XCD working set L2-fits — here that's natural N.
template<int ABF16>
__global__ __launch_bounds__(256)
void gemm_qkv_kernel(const void* __restrict__ Araw, const ushort* __restrict__ WT,
                     const float* __restrict__ bQ, const float* __restrict__ bK,
                     const float* __restrict__ bV,
                     ushort* __restrict__ Qb, ushort* __restrict__ Kb,
                     ushort* __restrict__ Vt)
{
    // slot s: As = smem + s*16384 (128x64), Bs = +8192. ctile aliases slot 0.
    __shared__ __align__(16) ushort smem[32768];   // 64 KB
    const int tid = threadIdx.x;
    const int m0  = blockIdx.y * 128;
    const int n0g = blockIdx.x * 128;          // 0..6143
    const int sel = n0g >> 11;                 // 0=Q 1=K 2=V
    const int n0  = n0g & 2047;
    const ushort* BT  = WT + (size_t)sel * WELEMS;
    const float* bias = (sel == 0) ? bQ : (sel == 1) ? bK : bV;
    const int w  = tid >> 6;
    const int l  = tid & 63;
    const int wy = w >> 1, wx = w & 1;
    const int q  = l >> 4, lm = l & 15;
    const int sw = lm & 7;                     // read-side XOR (row & 7 == lm & 7)

    f32x4 acc[4][4];
    #pragma unroll
    for (int i = 0; i < 4; ++i)
        #pragma unroll
        for (int j = 0; j < 4; ++j) acc[i][j] = (f32x4)0.0f;

    auto stage = [&](int slot, int kt) {
        ushort* AsS = smem + slot * 16384;
        ushort* BsS = AsS + 8192;
        if (ABF16) {
            #pragma unroll
            for (int it = 0; it < 4; ++it) {
                const int v = it * 256 + tid;       // 16B-chunk index 0..1023
                const int r = v >> 3;
                const int cs = ((v & 7) ^ (r & 7)) << 3;   // pre-swizzled src col
                const ushort* gA = (const ushort*)Araw + (size_t)(m0 + r) * HIDn + kt + cs;
                const ushort* gB = BT + (size_t)(n0 + r) * HIDn + kt + cs;
                GLOAD_LDS16(gA, AsS + (it * 256 + w * 64) * 8);
                GLOAD_LDS16(gB, BsS + (it * 256 + w * 64) * 8);
            }
        } else {
            #pragma unroll
            for (int it = 0; it < 4; ++it) {
                const int v = it * 256 + tid;
                const int r = v >> 3;
                const int c = (v & 7) << 3;
                const float* Af = (const float*)Araw + (size_t)(m0 + r) * HIDn + kt + c;
                const float4 a0 = *reinterpret_cast<const float4*>(Af);
                const float4 a1 = *reinterpret_cast<const float4*>(Af + 4);
                ushort* d = &AsS[(size_t)(v ^ (r & 7)) * 8];   // swizzled dest chunk
                d[0] = f2bf(a0.x); d[1] = f2bf(a0.y); d[2] = f2bf(a0.z); d[3] = f2bf(a0.w);
                d[4] = f2bf(a1.x); d[5] = f2bf(a1.y); d[6] = f2bf(a1.z); d[7] = f2bf(a1.w);
                const int cs = ((v & 7) ^ (r & 7)) << 3;
                const ushort* gB = BT + (size_t)(n0 + r) * HIDn + kt + cs;
                GLOAD_LDS16(gB, BsS + (it * 256 + w * 64) * 8);
            }
        }
    };

    auto compute = [&](int slot) {
        const ushort* AsS = smem + slot * 16384;
        const ushort* BsS = AsS + 8192;
        #pragma unroll
        for (int ks = 0; ks < 2; ++ks) {
            s16x8 af[4], bfv[4];
            #pragma unroll
            for (int im = 0; im < 4; ++im) {
                const int arow = wy * 64 + im * 16 + lm;
                af[im] = *reinterpret_cast<const s16x8*>(
                    &AsS[arow * 64 + (((ks * 4 + q) ^ sw) << 3)]);
            }
            #pragma unroll
            for (int in = 0; in < 4; ++in) {
                const int brow = wx * 64 + in * 16 + lm;
                bfv[in] = *reinterpret_cast<const s16x8*>(
                    &BsS[brow * 64 + (((ks * 4 + q) ^ sw) << 3)]);
            }
            __builtin_amdgcn_s_setprio(1);
            #pragma unroll
            for (int im = 0; im < 4; ++im)
                #pragma unroll
                for (int in = 0; in < 4; ++in)
                    acc[im][in] = __builtin_amdgcn_mfma_f32_16x16x32_bf16(af[im], bfv[in], acc[im][in], 0, 0, 0);
            __builtin_amdgcn_s_setprio(0);
        }
    };

    const int NT = HIDn / 64;   // 32
    stage(0, 0);
    int cur = 0;
    for (int t = 0; t < NT - 1; ++t) {
        stage(cur ^ 1, (t + 1) * 64);
        if (ABF16) asm volatile("s_waitcnt vmcnt(8)" ::: "memory");
        else       asm volatile("s_waitcnt vmcnt(4)" ::: "memory");
        __builtin_amdgcn_s_barrier();
        FENCE();
        compute(cur);
        FENCE();
        if (!ABF16) asm volatile("s_waitcnt lgkmcnt(0)" ::: "memory");
        __builtin_amdgcn_s_barrier();
        FENCE();
        cur ^= 1;
    }
    asm volatile("s_waitcnt vmcnt(0)" ::: "memory");
    __builtin_amdgcn_s_barrier();
    FENCE();
    compute(cur);
    __syncthreads();   // full fence before ctile aliases As/Bs

    if (sel == 2) {
        // LDS-transposed coalesced V store: ctile[d][s], stride 136 (2-way free).
        ushort* ctile = smem;
        #pragma unroll
        for (int in = 0; in < 4; ++in) {
            const int col = wx * 64 + in * 16 + lm;          // d
            const float bv = bias[n0 + col];
            #pragma unroll
            for (int im = 0; im < 4; ++im) {
                const int row0 = wy * 64 + im * 16 + q * 4;  // s-local
                #pragma unroll
                for (int r = 0; r < 4; ++r)
                    ctile[col * 136 + row0 + r] = f2bf(acc[im][in][r] + bv);
            }
        }
        __syncthreads();
        const int hh = n0 >> 7;
        const int bb = m0 >> 11;
        const int s0 = m0 & (SEQn - 1);
        const int st = (tid & 15) * 8;
        const int d0 = tid >> 4;            // 0..15
        #pragma unroll
        for (int db = 0; db < 8; ++db) {
            const int d = d0 + db * 16;
            const ushort4 v0 = *reinterpret_cast<const ushort4*>(&ctile[d * 136 + st]);
            const ushort4 v1 = *reinterpret_cast<const ushort4*>(&ctile[d * 136 + st + 4]);
            ushort* dstp = Vt + (((size_t)(bb * NHn + hh)) * HDn + d) * SEQn + s0 + st;
            *reinterpret_cast<ushort4*>(dstp)     = v0;
            *reinterpret_cast<ushort4*>(dstp + 4) = v1;
        }
    } else {
        ushort* ctile = smem;                  // 128 rows x stride 136
        #pragma unroll
        for (int in = 0; in < 4; ++in) {
            const int col = wx * 64 + in * 16 + lm;
            const float bv = bias[n0 + col];
            #pragma unroll
            for (int im = 0; im < 4; ++im) {
                const int row0 = wy * 64 + im * 16 + q * 4;
                #pragma unroll
                for (int r = 0; r < 4; ++r)
                    ctile[(row0 + r) * 136 + col] = f2bf(acc[im][in][r] + bv);
            }
        }
        __syncthreads();
        ushort* dst = (sel == 0) ? Qb : Kb;
        const int d = tid & 63;
        const float invf = exp2f(-(float)d * 0.20762050593046f);  // 10000^(-d/64)
        for (int r = tid >> 6; r < 128; r += 4) {
            const int s = (m0 + r) & (SEQn - 1);
            const float ang = (float)s * invf;
            float sn, cs;
            __sincosf(ang, &sn, &cs);
            const float t1 = bf2f(ctile[r * 136 + d]);
            const float t2 = bf2f(ctile[r * 136 + 64 + d]);
            const size_t base = (size_t)(m0 + r) * DMn + n0 + d;
            dst[base]      = f2bf(t1 * cs - t2 * sn);
            dst[base + 64] = f2bf(t1 * sn + t2 * cs);
        }
    }
}

// ---- final GEMM: out(4096x2048 fp32) = AO(bf16) * WT^T + bias (fp32) -------
// 128x128 tile, qkv T4 counted-vmcnt dbuf pipeline. Natural dispatch order
// (r4 lesson: XCD m-chunking streams B; natural n-striping keeps B L2-fit).
__global__ __launch_bounds__(256)
void gemm_out_kernel(const ushort* __restrict__ A, const ushort* __restrict__ BT,
                     const float* __restrict__ bias, float* __restrict__ C)
{
    __shared__ __align__(16) ushort smem[32768];   // 64 KB: 2 slots x (A 16K | B 16K)
    const int tid = threadIdx.x;
    const int m0 = blockIdx.y * 128;
    const int n0 = blockIdx.x * 128;
    const int w  = tid >> 6;
    const int l  = tid & 63;
    const int wy = w >> 1, wx = w & 1;
    const int q  = l >> 4, lm = l & 15;
    const int sw = lm & 7;

    f32x4 acc[4][4];
    #pragma unroll
    for (int i = 0; i < 4; ++i)
        #pragma unroll
        for (int j = 0; j < 4; ++j) acc[i][j] = (f32x4)0.0f;

    auto stage = [&](int slot, int kt) {
        ushort* AsS = smem + slot * 16384;
        ushort* BsS = AsS + 8192;
        #pragma unroll
        for (int it = 0; it < 4; ++it) {
            const int v = it * 256 + tid;
            const int r = v >> 3;
            const int cs = ((v & 7) ^ (r & 7)) << 3;
            GLOAD_LDS16(A  + (size_t)(m0 + r) * DMn + kt + cs,
                        AsS + (it * 256 + w * 64) * 8);
            GLOAD_LDS16(BT + (size_t)(n0 + r) * DMn + kt + cs,
                        BsS + (it * 256 + w * 64) * 8);
        }
    };

    auto compute = [&](int slot) {
        const ushort* AsS = smem + slot * 16384;
        const ushort* BsS = AsS + 8192;
        #pragma unroll
        for (int ks = 0; ks < 2; ++ks) {
            s16x8 af[4], bfv[4];
            #pragma unroll
            for (int im = 0; im < 4; ++im) {
                const int arow = wy * 64 + im * 16 + lm;
                af[im] = *reinterpret_cast<const s16x8*>(
                    &AsS[arow * 64 + (((ks * 4 + q) ^ sw) << 3)]);
            }
            #pragma unroll
            for (int in = 0; in < 4; ++in) {
                const int brow = wx * 64 + in * 16 + lm;
                bfv[in] = *reinterpret_cast<const s16x8*>(
                    &BsS[brow * 64 + (((ks * 4 + q) ^ sw) << 3)]);
            }
            __builtin_amdgcn_s_setprio(1);
            #pragma unroll
            for (int im = 0; im < 4; ++im)
                #pragma unroll
                for (int in = 0; in < 4; ++in)
                    acc[im][in] = __builtin_amdgcn_mfma_f32_16x16x32_bf16(af[im], bfv[in], acc[im][in], 0, 0, 0);
            __builtin_amdgcn_s_setprio(0);
        }
    };

    const int NT = DMn / 64;   // 32
    stage(0, 0);
    int cur = 0;
    for (int t = 0; t < NT - 1; ++t) {
        stage(cur ^ 1, (t + 1) * 64);
        asm volatile("s_waitcnt vmcnt(8)" ::: "memory");
        __builtin_amdgcn_s_barrier();
        FENCE();
        compute(cur);
        FENCE();
        __builtin_amdgcn_s_barrier();
        FENCE();
        cur ^= 1;
    }
    asm volatile("s_waitcnt vmcnt(0)" ::: "memory");
    __builtin_amdgcn_s_barrier();
    FENCE();
    compute(cur);

    #pragma unroll
    for (int in = 0; in < 4; ++in) {
        const int gcol = n0 + wx * 64 + in * 16 + lm;
        const float bv = bias[gcol];
        #pragma unroll
        for (int im = 0; im < 4; ++im) {
            const int grow0 = m0 + wy * 64 + im * 16 + q * 4;
            #pragma unroll
            for (int r = 0; r < 4; ++r)
                C[(size_t)(grow0 + r) * HIDn + gcol] = acc[im][in][r] + bv;
        }
    }
}

// -------- MFMA flash attention: r14 — TWO 16-query tiles per wave -----------
// 32 queries/wave share each K/V chunk: K+V loads and per-chunk overhead
// HALVE (35.2k -> 17.3k chunk-visits); the two independent softmax chains
// double ILP in the serial VALU section. MFMA count unchanged.
// XCD swizzle kept (mechanism-correct here: 4 (b,h) pairs = 4MB K+V per XCD).
__global__ __launch_bounds__(256)
void attn_mfma_kernel(const ushort* Q, const ushort* __restrict__ K,
                      const ushort* __restrict__ Vt, const float* __restrict__ kw,
                      ushort* AO)
{
    __shared__ ushort plds[4][2][16 * 40];   // per-wave, per-tile P; stride 40
    const int w  = threadIdx.x >> 6;
    const int l  = threadIdx.x & 63;
    const int q  = l >> 4, lm = l & 15;
    const int bid = blockIdx.x;                     // nwg = 512, cpx = 64
    const int swzb = (bid & 7) * 64 + (bid >> 3);
    const int gw = swzb * 4 + w;     // b(1) | h(4) | qt2(6)
    const int qt2 = gw & 63;
    const int h  = (gw >> 6) & (NHn - 1);
    const int b  = gw >> 10;
    const int q0 = qt2 * 32;
    const float f = kw[h] * 0.08838834764831845f;   // kw * HD^-0.5

    s16x8 qfA[4], qfB[4];
    const size_t qbaseA = ((size_t)(b * SEQn + q0 + lm)) * DMn + h * HDn;
    const size_t qbaseB = qbaseA + (size_t)16 * DMn;
    #pragma unroll
    for (int ks = 0; ks < 4; ++ks) {
        qfA[ks] = *reinterpret_cast<const s16x8*>(Q + qbaseA + ks * 32 + q * 8);
        qfB[ks] = *reinterpret_cast<const s16x8*>(Q + qbaseB + ks * 32 + q * 8);
    }

    f32x4 OA[8], OB[8];
    #pragma unroll
    for (int nt = 0; nt < 8; ++nt) { OA[nt] = (f32x4)0.0f; OB[nt] = (f32x4)0.0f; }
    float mA[4], mB[4], lA[4], lB[4];
    #pragma unroll
    for (int r = 0; r < 4; ++r) { mA[r] = -1e30f; mB[r] = -1e30f; lA[r] = 0.f; lB[r] = 0.f; }

    const int lo = q0 - WINn;              // q0, WINn multiples of 32
    const int c0 = lo > 0 ? lo : 0;
    const int nch = (q0 + 32 - c0) >> 5;

    const size_t kbh = ((size_t)(b * SEQn)) * DMn + h * HDn;
    const size_t vbh = ((size_t)(b * NHn + h)) * HDn * SEQn;

    for (int c = 0; c < nch; ++c) {
        const int kc = c0 + c * 32;
        // ---- prefetch V frags (shared by both q-tiles) ----
        s16x8 vf[8];
        #pragma unroll
        for (int nt = 0; nt < 8; ++nt)
            vf[nt] = *reinterpret_cast<const s16x8*>(
                Vt + vbh + (size_t)(nt * 16 + lm) * SEQn + kc + q * 8);
        // ---- QK^T: two 16-key tiles; K frags shared by both q-tiles ----
        f32x4 SA[2], SB[2];
        #pragma unroll
        for (int t = 0; t < 2; ++t) {
            f32x4 aA = (f32x4)0.0f, aB = (f32x4)0.0f;
            const size_t krow = kbh + (size_t)(kc + t * 16 + lm) * DMn;
            s16x8 kf[4];
            #pragma unroll
            for (int ks = 0; ks < 4; ++ks)
                kf[ks] = *reinterpret_cast<const s16x8*>(K + krow + ks * 32 + q * 8);
            __builtin_amdgcn_s_setprio(1);
            #pragma unroll
            for (int ks = 0; ks < 4; ++ks) {
                aA = __builtin_amdgcn_mfma_f32_16x16x32_bf16(qfA[ks], kf[ks], aA, 0, 0, 0);
                aB = __builtin_amdgcn_mfma_f32_16x16x32_bf16(qfB[ks], kf[ks], aB, 0, 0, 0);
            }
            __builtin_amdgcn_s_setprio(0);
            SA[t] = aA; SB[t] = aB;
        }
        // ---- scale, mask, online softmax (two independent chains) ----
        const int j0 = kc + lm, j1 = kc + 16 + lm;
        #pragma unroll
        for (int r = 0; r < 4; ++r) {
            // tile A: rows q0 + q*4 + r
            {
                const int i = q0 + q * 4 + r;
                float v0 = SA[0][r] * f;
                float v1 = SA[1][r] * f;
                if (j0 > i || j0 < i - WINn) v0 = -1e30f;
                if (j1 > i || j1 < i - WINn) v1 = -1e30f;
                float mx = fmaxf(v0, v1);
                #pragma unroll
                for (int off = 8; off > 0; off >>= 1)
                    mx = fmaxf(mx, __shfl_xor(mx, off));
                const float mn = fmaxf(mA[r], mx);
                const float alpha = __expf(mA[r] - mn);
                mA[r] = mn;
                const ushort h0 = f2bf(__expf(v0 - mn));
                const ushort h1 = f2bf(__expf(v1 - mn));
                plds[w][0][(q * 4 + r) * 40 + lm]      = h0;
                plds[w][0][(q * 4 + r) * 40 + 16 + lm] = h1;
                float ps = bf2f(h0) + bf2f(h1);
                #pragma unroll
                for (int off = 8; off > 0; off >>= 1)
                    ps += __shfl_xor(ps, off);
                lA[r] = lA[r] * alpha + ps;
                #pragma unroll
                for (int nt = 0; nt < 8; ++nt) OA[nt][r] *= alpha;
            }
            // tile B: rows q0 + 16 + q*4 + r
            {
                const int i = q0 + 16 + q * 4 + r;
                float v0 = SB[0][r] * f;
                float v1 = SB[1][r] * f;
                if (j0 > i || j0 < i - WINn) v0 = -1e30f;
                if (j1 > i || j1 < i - WINn) v1 = -1e30f;
                float mx = fmaxf(v0, v1);
                #pragma unroll
                for (int off = 8; off > 0; off >>= 1)
                    mx = fmaxf(mx, __shfl_xor(mx, off));
                const float mn = fmaxf(mB[r], mx);
                const float alpha = __expf(mB[r] - mn);
                mB[r] = mn;
                const ushort h0 = f2bf(__expf(v0 - mn));
                const ushort h1 = f2bf(__expf(v1 - mn));
                plds[w][1][(q * 4 + r) * 40 + lm]      = h0;
                plds[w][1][(q * 4 + r) * 40 + 16 + lm] = h1;
                float ps = bf2f(h0) + bf2f(h1);
                #pragma unroll
                for (int off = 8; off > 0; off >>= 1)
                    ps += __shfl_xor(ps, off);
                lB[r] = lB[r] * alpha + ps;
                #pragma unroll
                for (int nt = 0; nt < 8; ++nt) OB[nt][r] *= alpha;
            }
        }
        // ---- P -> A-frag via per-wave LDS round trip; P·V (shared vf) ----
        const s16x8 pfA = *reinterpret_cast<const s16x8*>(&plds[w][0][lm * 40 + q * 8]);
        const s16x8 pfB = *reinterpret_cast<const s16x8*>(&plds[w][1][lm * 40 + q * 8]);
        __builtin_amdgcn_s_setprio(1);
        #pragma unroll
        for (int nt = 0; nt < 8; ++nt) {
            OA[nt] = __builtin_amdgcn_mfma_f32_16x16x32_bf16(pfA, vf[nt], OA[nt], 0, 0, 0);
            OB[nt] = __builtin_amdgcn_mfma_f32_16x16x32_bf16(pfB, vf[nt], OB[nt], 0, 0, 0);
        }
        __builtin_amdgcn_s_setprio(0);
    }
    #pragma unroll
    for (int r = 0; r < 4; ++r) {
        const float invA = 1.0f / lA[r];
        const float invB = 1.0f / lB[r];
        const size_t orowA = ((size_t)(b * SEQn + q0 + q * 4 + r)) * DMn + h * HDn;
        const size_t orowB = orowA + (size_t)16 * DMn;
        #pragma unroll
        for (int nt = 0; nt < 8; ++nt) {
            AO[orowA + nt * 16 + lm] = f2bf(OA[nt][r] * invA);
            AO[orowB + nt * 16 + lm] = f2bf(OB[nt][r] * invB);
        }
    }
}

extern "C" void kernel_launch(void* const* d_in, const int* in_sizes, int n_in,
                              void* d_out, int out_size, void* d_ws, size_t ws_size,
                              hipStream_t stream)
{
    (void)in_sizes; (void)n_in; (void)out_size;
    const float* x  = (const float*)d_in[0];
    const float* WQ = (const float*)d_in[1];
    const float* bQ = (const float*)d_in[2];
    const float* WK = (const float*)d_in[3];
    const float* bK = (const float*)d_in[4];
    const float* WV = (const float*)d_in[5];
    const float* bV = (const float*)d_in[6];
    const float* WO = (const float*)d_in[7];
    const float* bO = (const float*)d_in[8];
    const float* kw = (const float*)d_in[9];
    float* out = (float*)d_out;

    // Full path: Qb/Kb/Vt (48 MB) + WT 4 slabs (32 MB) + xb (16 MB) = 96 MB.
    // Fallback (ws < 96 MB): 3 slabs, fp32-A QKV GEMM, late WO transpose.
    char* ws = (char*)d_ws;
    const size_t AELEMS = (size_t)MROWS * DMn;         // 4096*2048
    ushort* Qb = (ushort*)ws;                          // also AO (in-place)
    ushort* Kb = (ushort*)(ws + AELEMS * 2);
    ushort* Vt = (ushort*)(ws + AELEMS * 4);           // [b][h][d][s]
    ushort* WT = (ushort*)(ws + AELEMS * 6);           // up to 4 x 2048x2048 bf16
    const size_t FULL = AELEMS * 6 + WELEMS * 8 + AELEMS * 2;   // 96 MB
    const bool have_full = ws_size >= FULL;
    ushort* xb = (ushort*)(ws + AELEMS * 6 + WELEMS * 8);

    const dim3 tblk(32, 8);
    const int attn_grid = BATCHn * NHn * (SEQn / 32) / 4;   // 512

    if (have_full) {
        transpose_all_kernel<<<dim3(32, 32, 5), tblk, 0, stream>>>(WQ, WK, WV, WO, WT, x, xb);
        gemm_qkv_kernel<1><<<dim3(3 * DMn / 128, MROWS / 128), 256, 0, stream>>>(
            xb, WT, bQ, bK, bV, Qb, Kb, Vt);
        attn_mfma_kernel<<<dim3(attn_grid), 256, 0, stream>>>(Qb, Kb, Vt, kw, Qb);
        gemm_out_kernel<<<dim3(HIDn / 128, MROWS / 128), 256, 0, stream>>>(
            Qb, WT + 3 * WELEMS, bO, out);
    } else {
        transpose_all_kernel<<<dim3(32, 32, 3), tblk, 0, stream>>>(WQ, WK, WV, WO, WT, x, xb);
        gemm_qkv_kernel<0><<<dim3(3 * DMn / 128, MROWS / 128), 256, 0, stream>>>(
            x, WT, bQ, bK, bV, Qb, Kb, Vt);
        attn_mfma_kernel<<<dim3(attn_grid), 256, 0, stream>>>(Qb, Kb, Vt, kw, Qb);
        transpose_cvt_kernel<<<dim3(64, 64), tblk, 0, stream>>>(WO, WT);
        gemm_out_kernel<<<dim3(HIDn / 128, MROWS / 128), 256, 0, stream>>>(Qb, WT, bO, out);
    }
}

// Round 6
// 344.038 us; speedup vs baseline: 1.1083x; 1.0635x over previous
//
#include <hip/hip_runtime.h>
#include <cstdint>

#define SEQn   2048
#define NHn    16
#define HDn    128
#define DMn    2048   // NH*HD
#define HIDn   2048
#define BATCHn 2
#define WINn   256
#define MROWS  (BATCHn*SEQn)  // 4096
#define WELEMS ((size_t)HIDn * DMn)

typedef short s16x8 __attribute__((ext_vector_type(8)));  // 8 bf16 (4 VGPRs)
typedef float f32x4 __attribute__((ext_vector_type(4)));  // MFMA accumulator

__device__ __forceinline__ float bf2f(ushort x) {
    union { uint u; float f; } v; v.u = ((uint)x) << 16; return v.f;
}
__device__ __forceinline__ ushort f2bf(float f) {
    union { float f; uint u; } v; v.f = f;
    uint u = v.u;
    return (ushort)((u + 0x7FFFu + ((u >> 16) & 1u)) >> 16);  // RNE
}

// Direct global->LDS DMA, 16B per lane. Dest must be wave-uniform base,
// lane's 16B lands at base + lane*16 (linear! no padding allowed).
#define GLOAD_LDS16(g, l) __builtin_amdgcn_global_load_lds(                   \
    (const __attribute__((address_space(1))) unsigned int*)(g),               \
    (__attribute__((address_space(3))) unsigned int*)(l), 16, 0, 0)

// Compiler fence: no memory op or instruction crosses (rule #18 discipline —
// raw s_barrier is NOT a compiler fence; C++ ds_reads would hoist past it).
#define FENCE() do { asm volatile("" ::: "memory");                           \
                     __builtin_amdgcn_sched_barrier(0); } while (0)

// --- ONE up-front dispatch: z=0..3 transpose {WQ,WK,WV,WO} -> WT slabs,
//     z=4: x fp32 -> bf16.
// r15 W-path: float4 global reads (was 16 scalar loads/thread), t[n][k]
// stride-76 LDS (scatter writes ~4-way benign; k-contiguous ushort4 reads +
// coalesced ushort4 output writes preserved). Pure-BW kernel: instruction
// count cut ~2.5x. ---------------------------------------------------------
__global__ __launch_bounds__(256)
void transpose_all_kernel(const float* __restrict__ WQ, const float* __restrict__ WK,
                          const float* __restrict__ WV, const float* __restrict__ WO,
                          ushort* __restrict__ WT,
                          const float* __restrict__ x, ushort* __restrict__ xb)
{
    const int tid = threadIdx.y * 32 + threadIdx.x;
    if (blockIdx.z == 4) {
        const int bid = blockIdx.y * 32 + blockIdx.x;     // 0..1023
        const size_t b0 = (size_t)bid * 8192;
        #pragma unroll
        for (int i = 0; i < 4; ++i) {
            const size_t base = b0 + i * 2048 + tid * 8;
            const float4 a0 = *reinterpret_cast<const float4*>(x + base);
            const float4 a1 = *reinterpret_cast<const float4*>(x + base + 4);
            ushort4 o0, o1;
            o0.x = f2bf(a0.x); o0.y = f2bf(a0.y); o0.z = f2bf(a0.z); o0.w = f2bf(a0.w);
            o1.x = f2bf(a1.x); o1.y = f2bf(a1.y); o1.z = f2bf(a1.z); o1.w = f2bf(a1.w);
            *reinterpret_cast<ushort4*>(xb + base)     = o0;
            *reinterpret_cast<ushort4*>(xb + base + 4) = o1;
        }
        return;
    }
    __shared__ ushort t[64][76];   // [n][k], stride 76 (152B: 8B-aligned rows)
    const float* src = (blockIdx.z == 0) ? WQ : (blockIdx.z == 1) ? WK
                     : (blockIdx.z == 2) ? WV : WO;
    ushort* dst = WT + (size_t)blockIdx.z * WELEMS;
    const int n0 = blockIdx.x * 64;
    const int k0 = blockIdx.y * 64;
    const int c4 = (tid & 15) * 4;    // n-offset (float4 chunk)
    const int r0 = tid >> 4;          // 0..15 (k row)
    #pragma unroll
    for (int i = 0; i < 4; ++i) {
        const int r = r0 + i * 16;    // k
        const float4 a = *reinterpret_cast<const float4*>(
            src + (size_t)(k0 + r) * 2048 + n0 + c4);
        t[c4 + 0][r] = f2bf(a.x);
        t[c4 + 1][r] = f2bf(a.y);
        t[c4 + 2][r] = f2bf(a.z);
        t[c4 + 3][r] = f2bf(a.w);
    }
    __syncthreads();
    const int rowg = tid >> 4;        // 0..15  (n rows)
    const int kc   = (tid & 15) * 4;  // k chunk (ushort4)
    #pragma unroll
    for (int rr2 = 0; rr2 < 4; ++rr2) {
        const int arow = rowg + rr2 * 16;
        const ushort4 v = *reinterpret_cast<const ushort4*>(&t[arow][kc]);
        *reinterpret_cast<ushort4*>(dst + (size_t)(n0 + arow) * 2048 + k0 + kc) = v;
    }
}

// ------- single transpose+convert (fallback path only) -----------------------
__global__ __launch_bounds__(256)
void transpose_cvt_kernel(const float* __restrict__ src, ushort* __restrict__ dst)
{
    __shared__ ushort t[32][33];
    const int tx = threadIdx.x, ty = threadIdx.y;
    const int n  = blockIdx.x * 32 + tx;
    const int k0 = blockIdx.y * 32;
    #pragma unroll
    for (int r = ty; r < 32; r += 8)
        t[r][tx] = f2bf(src[(size_t)(k0 + r) * 2048 + n]);
    __syncthreads();
    const int k  = k0 + tx;
    const int nb = blockIdx.x * 32;
    #pragma unroll
    for (int r = ty; r < 32; r += 8)
        dst[(size_t)(nb + r) * 2048 + k] = t[tx][r];
}

// -------- fused QKV GEMM + fused RoPE epilogue ------------------------------
// T4 counted-vmcnt dbuf pipeline; 114.7us = this structure's ceiling
// (896 TF ~ m97-structure's 912 reference). Natural dispatch order (r4
// lesson: per-XCD n-stripe B is L2-fit; m-chunked swizzle streams B).
template<int ABF16>
__global__ __launch_bounds__(256)
void gemm_qkv_kernel(const void* __restrict__ Araw, const ushort* __restrict__ WT,
                     const float* __restrict__ bQ, const float* __restrict__ bK,
                     const float* __restrict__ bV,
                     ushort* __restrict__ Qb, ushort* __restrict__ Kb,
                     ushort* __restrict__ Vt)
{
    // slot s: As = smem + s*16384 (128x64), Bs = +8192. ctile aliases slot 0.
    __shared__ __align__(16) ushort smem[32768];   // 64 KB
    const int tid = threadIdx.x;
    const int m0  = blockIdx.y * 128;
    const int n0g = blockIdx.x * 128;          // 0..6143
    const int sel = n0g >> 11;                 // 0=Q 1=K 2=V
    const int n0  = n0g & 2047;
    const ushort* BT  = WT + (size_t)sel * WELEMS;
    const float* bias = (sel == 0) ? bQ : (sel == 1) ? bK : bV;
    const int w  = tid >> 6;
    const int l  = tid & 63;
    const int wy = w >> 1, wx = w & 1;
    const int q  = l >> 4, lm = l & 15;
    const int sw = lm & 7;                     // read-side XOR (row & 7 == lm & 7)

    f32x4 acc[4][4];
    #pragma unroll
    for (int i = 0; i < 4; ++i)
        #pragma unroll
        for (int j = 0; j < 4; ++j) acc[i][j] = (f32x4)0.0f;

    auto stage = [&](int slot, int kt) {
        ushort* AsS = smem + slot * 16384;
        ushort* BsS = AsS + 8192;
        if (ABF16) {
            #pragma unroll
            for (int it = 0; it < 4; ++it) {
                const int v = it * 256 + tid;       // 16B-chunk index 0..1023
                const int r = v >> 3;
                const int cs = ((v & 7) ^ (r & 7)) << 3;   // pre-swizzled src col
                const ushort* gA = (const ushort*)Araw + (size_t)(m0 + r) * HIDn + kt + cs;
                const ushort* gB = BT + (size_t)(n0 + r) * HIDn + kt + cs;
                GLOAD_LDS16(gA, AsS + (it * 256 + w * 64) * 8);
                GLOAD_LDS16(gB, BsS + (it * 256 + w * 64) * 8);
            }
        } else {
            #pragma unroll
            for (int it = 0; it < 4; ++it) {
                const int v = it * 256 + tid;
                const int r = v >> 3;
                const int c = (v & 7) << 3;
                const float* Af = (const float*)Araw + (size_t)(m0 + r) * HIDn + kt + c;
                const float4 a0 = *reinterpret_cast<const float4*>(Af);
                const float4 a1 = *reinterpret_cast<const float4*>(Af + 4);
                ushort* d = &AsS[(size_t)(v ^ (r & 7)) * 8];   // swizzled dest chunk
                d[0] = f2bf(a0.x); d[1] = f2bf(a0.y); d[2] = f2bf(a0.z); d[3] = f2bf(a0.w);
                d[4] = f2bf(a1.x); d[5] = f2bf(a1.y); d[6] = f2bf(a1.z); d[7] = f2bf(a1.w);
                const int cs = ((v & 7) ^ (r & 7)) << 3;
                const ushort* gB = BT + (size_t)(n0 + r) * HIDn + kt + cs;
                GLOAD_LDS16(gB, BsS + (it * 256 + w * 64) * 8);
            }
        }
    };

    auto compute = [&](int slot) {
        const ushort* AsS = smem + slot * 16384;
        const ushort* BsS = AsS + 8192;
        #pragma unroll
        for (int ks = 0; ks < 2; ++ks) {
            s16x8 af[4], bfv[4];
            #pragma unroll
            for (int im = 0; im < 4; ++im) {
                const int arow = wy * 64 + im * 16 + lm;
                af[im] = *reinterpret_cast<const s16x8*>(
                    &AsS[arow * 64 + (((ks * 4 + q) ^ sw) << 3)]);
            }
            #pragma unroll
            for (int in = 0; in < 4; ++in) {
                const int brow = wx * 64 + in * 16 + lm;
                bfv[in] = *reinterpret_cast<const s16x8*>(
                    &BsS[brow * 64 + (((ks * 4 + q) ^ sw) << 3)]);
            }
            __builtin_amdgcn_s_setprio(1);
            #pragma unroll
            for (int im = 0; im < 4; ++im)
                #pragma unroll
                for (int in = 0; in < 4; ++in)
                    acc[im][in] = __builtin_amdgcn_mfma_f32_16x16x32_bf16(af[im], bfv[in], acc[im][in], 0, 0, 0);
            __builtin_amdgcn_s_setprio(0);
        }
    };

    const int NT = HIDn / 64;   // 32
    stage(0, 0);
    int cur = 0;
    for (int t = 0; t < NT - 1; ++t) {
        stage(cur ^ 1, (t + 1) * 64);
        if (ABF16) asm volatile("s_waitcnt vmcnt(8)" ::: "memory");
        else       asm volatile("s_waitcnt vmcnt(4)" ::: "memory");
        __builtin_amdgcn_s_barrier();
        FENCE();
        compute(cur);
        FENCE();
        if (!ABF16) asm volatile("s_waitcnt lgkmcnt(0)" ::: "memory");
        __builtin_amdgcn_s_barrier();
        FENCE();
        cur ^= 1;
    }
    asm volatile("s_waitcnt vmcnt(0)" ::: "memory");
    __builtin_amdgcn_s_barrier();
    FENCE();
    compute(cur);
    __syncthreads();   // full fence before ctile aliases As/Bs

    if (sel == 2) {
        // LDS-transposed coalesced V store: ctile[d][s], stride 136 (2-way free).
        ushort* ctile = smem;
        #pragma unroll
        for (int in = 0; in < 4; ++in) {
            const int col = wx * 64 + in * 16 + lm;          // d
            const float bv = bias[n0 + col];
            #pragma unroll
            for (int im = 0; im < 4; ++im) {
                const int row0 = wy * 64 + im * 16 + q * 4;  // s-local
                #pragma unroll
                for (int r = 0; r < 4; ++r)
                    ctile[col * 136 + row0 + r] = f2bf(acc[im][in][r] + bv);
            }
        }
        __syncthreads();
        const int hh = n0 >> 7;
        const int bb = m0 >> 11;
        const int s0 = m0 & (SEQn - 1);
        const int st = (tid & 15) * 8;
        const int d0 = tid >> 4;            // 0..15
        #pragma unroll
        for (int db = 0; db < 8; ++db) {
            const int d = d0 + db * 16;
            const ushort4 v0 = *reinterpret_cast<const ushort4*>(&ctile[d * 136 + st]);
            const ushort4 v1 = *reinterpret_cast<const ushort4*>(&ctile[d * 136 + st + 4]);
            ushort* dstp = Vt + (((size_t)(bb * NHn + hh)) * HDn + d) * SEQn + s0 + st;
            *reinterpret_cast<ushort4*>(dstp)     = v0;
            *reinterpret_cast<ushort4*>(dstp + 4) = v1;
        }
    } else {
        ushort* ctile = smem;                  // 128 rows x stride 136
        #pragma unroll
        for (int in = 0; in < 4; ++in) {
            const int col = wx * 64 + in * 16 + lm;
            const float bv = bias[n0 + col];
            #pragma unroll
            for (int im = 0; im < 4; ++im) {
                const int row0 = wy * 64 + im * 16 + q * 4;
                #pragma unroll
                for (int r = 0; r < 4; ++r)
                    ctile[(row0 + r) * 136 + col] = f2bf(acc[im][in][r] + bv);
            }
        }
        __syncthreads();
        ushort* dst = (sel == 0) ? Qb : Kb;
        const int d = tid & 63;
        const float invf = exp2f(-(float)d * 0.20762050593046f);  // 10000^(-d/64)
        for (int r = tid >> 6; r < 128; r += 4) {
            const int s = (m0 + r) & (SEQn - 1);
            const float ang = (float)s * invf;
            float sn, cs;
            __sincosf(ang, &sn, &cs);
            const float t1 = bf2f(ctile[r * 136 + d]);
            const float t2 = bf2f(ctile[r * 136 + 64 + d]);
            const size_t base = (size_t)(m0 + r) * DMn + n0 + d;
            dst[base]      = f2bf(t1 * cs - t2 * sn);
            dst[base + 64] = f2bf(t1 * sn + t2 * cs);
        }
    }
}

// ---- final GEMM: out(4096x2048 fp32) = AO(bf16) * WT^T + bias (fp32) -------
// 128x128 tile, qkv T4 counted-vmcnt dbuf pipeline. Natural dispatch order.
__global__ __launch_bounds__(256)
void gemm_out_kernel(const ushort* __restrict__ A, const ushort* __restrict__ BT,
                     const float* __restrict__ bias, float* __restrict__ C)
{
    __shared__ __align__(16) ushort smem[32768];   // 64 KB: 2 slots x (A 16K | B 16K)
    const int tid = threadIdx.x;
    const int m0 = blockIdx.y * 128;
    const int n0 = blockIdx.x * 128;
    const int w  = tid >> 6;
    const int l  = tid & 63;
    const int wy = w >> 1, wx = w & 1;
    const int q  = l >> 4, lm = l & 15;
    const int sw = lm & 7;

    f32x4 acc[4][4];
    #pragma unroll
    for (int i = 0; i < 4; ++i)
        #pragma unroll
        for (int j = 0; j < 4; ++j) acc[i][j] = (f32x4)0.0f;

    auto stage = [&](int slot, int kt) {
        ushort* AsS = smem + slot * 16384;
        ushort* BsS = AsS + 8192;
        #pragma unroll
        for (int it = 0; it < 4; ++it) {
            const int v = it * 256 + tid;
            const int r = v >> 3;
            const int cs = ((v & 7) ^ (r & 7)) << 3;
            GLOAD_LDS16(A  + (size_t)(m0 + r) * DMn + kt + cs,
                        AsS + (it * 256 + w * 64) * 8);
            GLOAD_LDS16(BT + (size_t)(n0 + r) * DMn + kt + cs,
                        BsS + (it * 256 + w * 64) * 8);
        }
    };

    auto compute = [&](int slot) {
        const ushort* AsS = smem + slot * 16384;
        const ushort* BsS = AsS + 8192;
        #pragma unroll
        for (int ks = 0; ks < 2; ++ks) {
            s16x8 af[4], bfv[4];
            #pragma unroll
            for (int im = 0; im < 4; ++im) {
                const int arow = wy * 64 + im * 16 + lm;
                af[im] = *reinterpret_cast<const s16x8*>(
                    &AsS[arow * 64 + (((ks * 4 + q) ^ sw) << 3)]);
            }
            #pragma unroll
            for (int in = 0; in < 4; ++in) {
                const int brow = wx * 64 + in * 16 + lm;
                bfv[in] = *reinterpret_cast<const s16x8*>(
                    &BsS[brow * 64 + (((ks * 4 + q) ^ sw) << 3)]);
            }
            __builtin_amdgcn_s_setprio(1);
            #pragma unroll
            for (int im = 0; im < 4; ++im)
                #pragma unroll
                for (int in = 0; in < 4; ++in)
                    acc[im][in] = __builtin_amdgcn_mfma_f32_16x16x32_bf16(af[im], bfv[in], acc[im][in], 0, 0, 0);
            __builtin_amdgcn_s_setprio(0);
        }
    };

    const int NT = DMn / 64;   // 32
    stage(0, 0);
    int cur = 0;
    for (int t = 0; t < NT - 1; ++t) {
        stage(cur ^ 1, (t + 1) * 64);
        asm volatile("s_waitcnt vmcnt(8)" ::: "memory");
        __builtin_amdgcn_s_barrier();
        FENCE();
        compute(cur);
        FENCE();
        __builtin_amdgcn_s_barrier();
        FENCE();
        cur ^= 1;
    }
    asm volatile("s_waitcnt vmcnt(0)" ::: "memory");
    __builtin_amdgcn_s_barrier();
    FENCE();
    compute(cur);

    #pragma unroll
    for (int in = 0; in < 4; ++in) {
        const int gcol = n0 + wx * 64 + in * 16 + lm;
        const float bv = bias[gcol];
        #pragma unroll
        for (int im = 0; im < 4; ++im) {
            const int grow0 = m0 + wy * 64 + im * 16 + q * 4;
            #pragma unroll
            for (int r = 0; r < 4; ++r)
                C[(size_t)(grow0 + r) * HIDn + gcol] = acc[im][in][r] + bv;
        }
    }
}

// -------- MFMA flash attention: TWO 16-query tiles per wave -----------------
// r15: ALL K-frag loads (both 16-key tiles) hoisted to chunk top with the V
// prefetch — previously kf was loaded inside the t-loop right before its
// MFMA, exposing ~200-500cy L2 latency twice per chunk. Now the 16 global
// loads issue together and their latency hides under the softmax + prior PV.
// +16 VGPR, intra-iteration only.
__global__ __launch_bounds__(256)
void attn_mfma_kernel(const ushort* Q, const ushort* __restrict__ K,
                      const ushort* __restrict__ Vt, const float* __restrict__ kw,
                      ushort* AO)
{
    __shared__ ushort plds[4][2][16 * 40];   // per-wave, per-tile P; stride 40
    const int w  = threadIdx.x >> 6;
    const int l  = threadIdx.x & 63;
    const int q  = l >> 4, lm = l & 15;
    const int bid = blockIdx.x;                     // nwg = 512, cpx = 64
    const int swzb = (bid & 7) * 64 + (bid >> 3);
    const int gw = swzb * 4 + w;     // b(1) | h(4) | qt2(6)
    const int qt2 = gw & 63;
    const int h  = (gw >> 6) & (NHn - 1);
    const int b  = gw >> 10;
    const int q0 = qt2 * 32;
    const float f = kw[h] * 0.08838834764831845f;   // kw * HD^-0.5

    s16x8 qfA[4], qfB[4];
    const size_t qbaseA = ((size_t)(b * SEQn + q0 + lm)) * DMn + h * HDn;
    const size_t qbaseB = qbaseA + (size_t)16 * DMn;
    #pragma unroll
    for (int ks = 0; ks < 4; ++ks) {
        qfA[ks] = *reinterpret_cast<const s16x8*>(Q + qbaseA + ks * 32 + q * 8);
        qfB[ks] = *reinterpret_cast<const s16x8*>(Q + qbaseB + ks * 32 + q * 8);
    }

    f32x4 OA[8], OB[8];
    #pragma unroll
    for (int nt = 0; nt < 8; ++nt) { OA[nt] = (f32x4)0.0f; OB[nt] = (f32x4)0.0f; }
    float mA[4], mB[4], lA[4], lB[4];
    #pragma unroll
    for (int r = 0; r < 4; ++r) { mA[r] = -1e30f; mB[r] = -1e30f; lA[r] = 0.f; lB[r] = 0.f; }

    const int lo = q0 - WINn;              // q0, WINn multiples of 32
    const int c0 = lo > 0 ? lo : 0;
    const int nch = (q0 + 32 - c0) >> 5;

    const size_t kbh = ((size_t)(b * SEQn)) * DMn + h * HDn;
    const size_t vbh = ((size_t)(b * NHn + h)) * HDn * SEQn;

    for (int c = 0; c < nch; ++c) {
        const int kc = c0 + c * 32;
        // ---- prefetch ALL of this chunk's V and K frags together ----
        s16x8 vf[8], kf0[4], kf1[4];
        #pragma unroll
        for (int nt = 0; nt < 8; ++nt)
            vf[nt] = *reinterpret_cast<const s16x8*>(
                Vt + vbh + (size_t)(nt * 16 + lm) * SEQn + kc + q * 8);
        {
            const size_t krow0 = kbh + (size_t)(kc + lm) * DMn;
            const size_t krow1 = kbh + (size_t)(kc + 16 + lm) * DMn;
            #pragma unroll
            for (int ks = 0; ks < 4; ++ks) {
                kf0[ks] = *reinterpret_cast<const s16x8*>(K + krow0 + ks * 32 + q * 8);
                kf1[ks] = *reinterpret_cast<const s16x8*>(K + krow1 + ks * 32 + q * 8);
            }
        }
        // ---- QK^T: two 16-key tiles; K frags shared by both q-tiles ----
        f32x4 SA[2], SB[2];
        {
            f32x4 aA0 = (f32x4)0.0f, aB0 = (f32x4)0.0f;
            f32x4 aA1 = (f32x4)0.0f, aB1 = (f32x4)0.0f;
            __builtin_amdgcn_s_setprio(1);
            #pragma unroll
            for (int ks = 0; ks < 4; ++ks) {
                aA0 = __builtin_amdgcn_mfma_f32_16x16x32_bf16(qfA[ks], kf0[ks], aA0, 0, 0, 0);
                aB0 = __builtin_amdgcn_mfma_f32_16x16x32_bf16(qfB[ks], kf0[ks], aB0, 0, 0, 0);
                aA1 = __builtin_amdgcn_mfma_f32_16x16x32_bf16(qfA[ks], kf1[ks], aA1, 0, 0, 0);
                aB1 = __builtin_amdgcn_mfma_f32_16x16x32_bf16(qfB[ks], kf1[ks], aB1, 0, 0, 0);
            }
            __builtin_amdgcn_s_setprio(0);
            SA[0] = aA0; SA[1] = aA1; SB[0] = aB0; SB[1] = aB1;
        }
        // ---- scale, mask, online softmax (two independent chains) ----
        const int j0 = kc + lm, j1 = kc + 16 + lm;
        #pragma unroll
        for (int r = 0; r < 4; ++r) {
            // tile A: rows q0 + q*4 + r
            {
                const int i = q0 + q * 4 + r;
                float v0 = SA[0][r] * f;
                float v1 = SA[1][r] * f;
                if (j0 > i || j0 < i - WINn) v0 = -1e30f;
                if (j1 > i || j1 < i - WINn) v1 = -1e30f;
                float mx = fmaxf(v0, v1);
                #pragma unroll
                for (int off = 8; off > 0; off >>= 1)
                    mx = fmaxf(mx, __shfl_xor(mx, off));
                const float mn = fmaxf(mA[r], mx);
                const float alpha = __expf(mA[r] - mn);
                mA[r] = mn;
                const ushort h0 = f2bf(__expf(v0 - mn));
                const ushort h1 = f2bf(__expf(v1 - mn));
                plds[w][0][(q * 4 + r) * 40 + lm]      = h0;
                plds[w][0][(q * 4 + r) * 40 + 16 + lm] = h1;
                float ps = bf2f(h0) + bf2f(h1);
                #pragma unroll
                for (int off = 8; off > 0; off >>= 1)
                    ps += __shfl_xor(ps, off);
                lA[r] = lA[r] * alpha + ps;
                #pragma unroll
                for (int nt = 0; nt < 8; ++nt) OA[nt][r] *= alpha;
            }
            // tile B: rows q0 + 16 + q*4 + r
            {
                const int i = q0 + 16 + q * 4 + r;
                float v0 = SB[0][r] * f;
                float v1 = SB[1][r] * f;
                if (j0 > i || j0 < i - WINn) v0 = -1e30f;
                if (j1 > i || j1 < i - WINn) v1 = -1e30f;
                float mx = fmaxf(v0, v1);
                #pragma unroll
                for (int off = 8; off > 0; off >>= 1)
                    mx = fmaxf(mx, __shfl_xor(mx, off));
                const float mn = fmaxf(mB[r], mx);
                const float alpha = __expf(mB[r] - mn);
                mB[r] = mn;
                const ushort h0 = f2bf(__expf(v0 - mn));
                const ushort h1 = f2bf(__expf(v1 - mn));
                plds[w][1][(q * 4 + r) * 40 + lm]      = h0;
                plds[w][1][(q * 4 + r) * 40 + 16 + lm] = h1;
                float ps = bf2f(h0) + bf2f(h1);
                #pragma unroll
                for (int off = 8; off > 0; off >>= 1)
                    ps += __shfl_xor(ps, off);
                lB[r] = lB[r] * alpha + ps;
                #pragma unroll
                for (int nt = 0; nt < 8; ++nt) OB[nt][r] *= alpha;
            }
        }
        // ---- P -> A-frag via per-wave LDS round trip; P·V (shared vf) ----
        const s16x8 pfA = *reinterpret_cast<const s16x8*>(&plds[w][0][lm * 40 + q * 8]);
        const s16x8 pfB = *reinterpret_cast<const s16x8*>(&plds[w][1][lm * 40 + q * 8]);
        __builtin_amdgcn_s_setprio(1);
        #pragma unroll
        for (int nt = 0; nt < 8; ++nt) {
            OA[nt] = __builtin_amdgcn_mfma_f32_16x16x32_bf16(pfA, vf[nt], OA[nt], 0, 0, 0);
            OB[nt] = __builtin_amdgcn_mfma_f32_16x16x32_bf16(pfB, vf[nt], OB[nt], 0, 0, 0);
        }
        __builtin_amdgcn_s_setprio(0);
    }
    #pragma unroll
    for (int r = 0; r < 4; ++r) {
        const float invA = 1.0f / lA[r];
        const float invB = 1.0f / lB[r];
        const size_t orowA = ((size_t)(b * SEQn + q0 + q * 4 + r)) * DMn + h * HDn;
        const size_t orowB = orowA + (size_t)16 * DMn;
        #pragma unroll
        for (int nt = 0; nt < 8; ++nt) {
            AO[orowA + nt * 16 + lm] = f2bf(OA[nt][r] * invA);
            AO[orowB + nt * 16 + lm] = f2bf(OB[nt][r] * invB);
        }
    }
}

extern "C" void kernel_launch(void* const* d_in, const int* in_sizes, int n_in,
                              void* d_out, int out_size, void* d_ws, size_t ws_size,
                              hipStream_t stream)
{
    (void)in_sizes; (void)n_in; (void)out_size;
    const float* x  = (const float*)d_in[0];
    const float* WQ = (const float*)d_in[1];
    const float* bQ = (const float*)d_in[2];
    const float* WK = (const float*)d_in[3];
    const float* bK = (const float*)d_in[4];
    const float* WV = (const float*)d_in[5];
    const float* bV = (const float*)d_in[6];
    const float* WO = (const float*)d_in[7];
    const float* bO = (const float*)d_in[8];
    const float* kw = (const float*)d_in[9];
    float* out = (float*)d_out;

    // Full path: Qb/Kb/Vt (48 MB) + WT 4 slabs (32 MB) + xb (16 MB) = 96 MB.
    // Fallback (ws < 96 MB): 3 slabs, fp32-A QKV GEMM, late WO transpose.
    char* ws = (char*)d_ws;
    const size_t AELEMS = (size_t)MROWS * DMn;         // 4096*2048
    ushort* Qb = (ushort*)ws;                          // also AO (in-place)
    ushort* Kb = (ushort*)(ws + AELEMS * 2);
    ushort* Vt = (ushort*)(ws + AELEMS * 4);           // [b][h][d][s]
    ushort* WT = (ushort*)(ws + AELEMS * 6);           // up to 4 x 2048x2048 bf16
    const size_t FULL = AELEMS * 6 + WELEMS * 8 + AELEMS * 2;   // 96 MB
    const bool have_full = ws_size >= FULL;
    ushort* xb = (ushort*)(ws + AELEMS * 6 + WELEMS * 8);

    const dim3 tblk(32, 8);
    const int attn_grid = BATCHn * NHn * (SEQn / 32) / 4;   // 512

    if (have_full) {
        transpose_all_kernel<<<dim3(32, 32, 5), tblk, 0, stream>>>(WQ, WK, WV, WO, WT, x, xb);
        gemm_qkv_kernel<1><<<dim3(3 * DMn / 128, MROWS / 128), 256, 0, stream>>>(
            xb, WT, bQ, bK, bV, Qb, Kb, Vt);
        attn_mfma_kernel<<<dim3(attn_grid), 256, 0, stream>>>(Qb, Kb, Vt, kw, Qb);
        gemm_out_kernel<<<dim3(HIDn / 128, MROWS / 128), 256, 0, stream>>>(
            Qb, WT + 3 * WELEMS, bO, out);
    } else {
        transpose_all_kernel<<<dim3(32, 32, 3), tblk, 0, stream>>>(WQ, WK, WV, WO, WT, x, xb);
        gemm_qkv_kernel<0><<<dim3(3 * DMn / 128, MROWS / 128), 256, 0, stream>>>(
            x, WT, bQ, bK, bV, Qb, Kb, Vt);
        attn_mfma_kernel<<<dim3(attn_grid), 256, 0, stream>>>(Qb, Kb, Vt, kw, Qb);
        transpose_cvt_kernel<<<dim3(64, 64), tblk, 0, stream>>>(WO, WT);
        gemm_out_kernel<<<dim3(HIDn / 128, MROWS / 128), 256, 0, stream>>>(Qb, WT, bO, out);
    }
}